// Round 1
// baseline (98.671 us; speedup 1.0000x reference)
//
#include <hip/hip_runtime.h>
#include <math.h>

#define BLOCK 256

__global__ __launch_bounds__(BLOCK) void yolo_decode_kernel(
    const float* __restrict__ x,
    const float* __restrict__ anchors,
    float* __restrict__ out,
    int total)
{
    constexpr int G   = 152;
    constexpr int GG  = G * G;        // 23104
    constexpr int NUM = 3;
    constexpr int CPA = 14;           // channels per anchor
    constexpr float STRIDE = 4.0f;    // 608 / 152

    __shared__ float lds[BLOCK * 15];

    const int tid = threadIdx.x;
    const int p   = blockIdx.x * BLOCK + tid;

    float vals[15];

    if (p < total) {
        // decompose p -> (b, n, s) with s = gy*G + gx
        int b   = p / (NUM * GG);
        int rem = p - b * (NUM * GG);
        int n   = rem / GG;
        int s   = rem - n * GG;
        int gy  = s / G;
        int gx  = s - gy * G;

        const float* xp = x + (size_t)b * (NUM * CPA * GG) + (size_t)(n * CPA) * GG + (size_t)s;

        float t0 = xp[0 * GG];
        float t1 = xp[1 * GG];
        float t2 = xp[2 * GG];
        float t3 = xp[3 * GG];
        float im = xp[4 * GG];
        float re = xp[5 * GG];
        float t6 = xp[6 * GG];

        float offx = 1.0f / (1.0f + __expf(-t0));
        float offy = 1.0f / (1.0f + __expf(-t1));
        float aw   = __expf(t2) * anchors[n * 2 + 0];
        float ah   = __expf(t3) * anchors[n * 2 + 1];
        float conf = 1.0f / (1.0f + __expf(-t6));
        float yaw  = atanf(im / re);
        float ax   = floorf((offx + (float)gx) * STRIDE);
        float ay   = floorf((offy + (float)gy) * STRIDE);

        vals[0] = im;   vals[1] = re;
        vals[2] = yaw;  vals[3] = conf;
        vals[4] = ax;   vals[5] = ay;
        vals[6] = aw;   vals[7] = ah;

        // scrambled cls channels (faithful to reference reshape):
        //   out[..., f] = x[b, n_src*14 + 7 + k, gy, gx]
        //   idx = 3*(f-8) + n, n_src = idx/7, k = idx%7
        const float* xcb = x + (size_t)b * (NUM * CPA * GG) + (size_t)s;
        #pragma unroll
        for (int f = 8; f < 15; ++f) {
            int idx  = 3 * (f - 8) + n;       // 0..20
            int nsrc = idx / 7;
            int k    = idx - 7 * nsrc;
            vals[f]  = xcb[(size_t)(nsrc * CPA + 7 + k) * GG];
        }
    } else {
        #pragma unroll
        for (int f = 0; f < 15; ++f) vals[f] = 0.0f;
    }

    // stage in LDS: stride 15 (coprime with 32 banks -> 2 lanes/bank, free)
    #pragma unroll
    for (int f = 0; f < 15; ++f) lds[tid * 15 + f] = vals[f];
    __syncthreads();

    // coalesced flush: BLOCK*15 floats = 960 x float4
    const size_t blockbase = (size_t)blockIdx.x * (BLOCK * 15);
    const size_t out_total = (size_t)total * 15;

    if (blockbase + (size_t)(BLOCK * 15) <= out_total) {
        const float4* l4 = (const float4*)lds;
        float4* o4 = (float4*)(out + blockbase);
        #pragma unroll
        for (int j = tid; j < BLOCK * 15 / 4; j += BLOCK) o4[j] = l4[j];
    } else {
        size_t nrem = out_total - blockbase;
        for (size_t j = tid; j < nrem; j += BLOCK) out[blockbase + j] = lds[j];
    }
}

extern "C" void kernel_launch(void* const* d_in, const int* in_sizes, int n_in,
                              void* d_out, int out_size, void* d_ws, size_t ws_size,
                              hipStream_t stream) {
    const float* x       = (const float*)d_in[0];
    const float* anchors = (const float*)d_in[1];
    float* out           = (float*)d_out;

    const int total = in_sizes[0] / 14;            // B*NUM*G*G positions
    const int grid  = (total + BLOCK - 1) / BLOCK; // 17328 for this shape

    yolo_decode_kernel<<<grid, BLOCK, 0, stream>>>(x, anchors, out, total);
}